// Round 1
// 126.628 us; speedup vs baseline: 1.0030x; 1.0030x over previous
//
#include <hip/hip_runtime.h>
#include <math.h>

// Problem constants: B=32, T=2048, J=64, D=256 (fp32 in/out)
#define BQ 32
#define TQ 2048
#define JQ 64
#define DQ 256
#define NBLK1 2048  // K1: 64 chunks of 32 t-rows per batch
#define NBLK2 1024  // K2: 32 chunks of 64 t-rows per batch (write stream)
#define NTHR 256

typedef float f4 __attribute__((ext_vector_type(4)));  // native vec for nt ld/st

// pooled[b,:] = (sum_t e_t*h_t) / (sum_t e_t), e = exp(max_j s); normalization
// deferred to K2. ws: dpart[NBLK1] | ppart[NBLK1*DQ] — all written before read
// (poison-safe). Cross-kernel visibility via the kernel boundary (grid.sync
// leaves stale per-XCD L2).

// ---------------------------------------------------------------------------
// K1 (v2): wave-self-contained. Wave w owns rows w*8..w*8+7 of the chunk:
// computes their rowmax/exp with shuffles only (NO cross-wave sync, no e_lds),
// then pools its own 8 h-rows. Single __syncthreads for the cross-wave sum.
// Removes the s-phase -> h-phase barrier bubble of v1.
// ---------------------------------------------------------------------------
__global__ __launch_bounds__(NTHR) void k_fused_pool(
    const f4* __restrict__ s4, const f4* __restrict__ h4,
    float* __restrict__ dpart, float* __restrict__ ppart)
{
    const int blk = blockIdx.x, tid = threadIdx.x;
    const int b = blk >> 6;                           // 64 chunks per batch
    const int t0 = (blk & 63) * 32;
    const int w = tid >> 6;                           // wave 0..3
    const int lane = tid & 63;

    // --- s-phase: wave w, pass p covers rows w*8+p*4 .. +3 (1 KiB/instr) ---
    // lane group g=lane>>4 holds row w*8+p*4+g; 16-lane xor-reduce -> rowmax.
    float e[2];
    #pragma unroll
    for (int p = 0; p < 2; ++p) {
        int idx = blk * 512 + w * 128 + p * 64 + lane;    // f4 index into s
        f4 v = __builtin_nontemporal_load(&s4[idx]);
        float m = fmaxf(fmaxf(v.x, v.y), fmaxf(v.z, v.w));
        m = fmaxf(m, __shfl_xor(m, 1));
        m = fmaxf(m, __shfl_xor(m, 2));
        m = fmaxf(m, __shfl_xor(m, 4));
        m = fmaxf(m, __shfl_xor(m, 8));
        e[p] = expf(m);                               // group-uniform, z1<=~5.5
    }
    // wave-partial denominator: sum of this wave's 8 e values
    float dw = e[0] + e[1];                           // two rows per lane group
    dw += __shfl_xor(dw, 16);                         // combine groups g^1
    dw += __shfl_xor(dw, 32);                         // combine groups g^2

    // --- pool: wave w accumulates its own 8 rows over full D (no barrier) ---
    f4 acc = (f4)(0.f);
    #pragma unroll
    for (int j = 0; j < 8; ++j) {
        float wt = __shfl(e[j >> 2], (j & 3) << 4);   // broadcast row w*8+j's e
        int tl = w * 8 + j;
        f4 hv = __builtin_nontemporal_load(
            &h4[(size_t)(b * TQ + t0 + tl) * (DQ / 4) + lane]);
        acc += wt * hv;
    }

    // --- single cross-wave reduction ---
    __shared__ float sred[NTHR][4];
    __shared__ float dred[4];
    sred[tid][0] = acc.x; sred[tid][1] = acc.y;
    sred[tid][2] = acc.z; sred[tid][3] = acc.w;
    if (lane == 0) dred[w] = dw;
    __syncthreads();
    int dd4 = tid >> 2, c4 = tid & 3;                 // tid <-> d in [0,256)
    float sum = sred[dd4][c4] + sred[64 + dd4][c4] +
                sred[128 + dd4][c4] + sred[192 + dd4][c4];
    ppart[blk * DQ + tid] = sum;                      // deterministic, no atomics
    if (tid == 0)
        dpart[blk] = (dred[0] + dred[1]) + (dred[2] + dred[3]);
}

// ---------------------------------------------------------------------------
// K2 (v2): pooled[b,:] = (sum of batch's 64 ppart slices) / (sum of 64 dpart),
// redundantly per block (L2/L3-hot, ~65 KiB). Read phase vectorized: 16 f4
// loads/thread (was 64 b32) + one LDS reduce -> shorter pre-store critical
// path. Then broadcast to the block's 64-t out slice with nt f4 stores.
// ---------------------------------------------------------------------------
__global__ __launch_bounds__(NTHR) void k_reduce_bcast(
    const float* __restrict__ dpart, const f4* __restrict__ ppart4,
    f4* __restrict__ out4)
{
    const int blk = blockIdx.x, tid = threadIdx.x;
    const int b = blk >> 5;                           // 32 out-chunks per batch
    const int w = tid >> 6, lane = tid & 63;
    __shared__ __align__(16) f4 pp[NTHR];             // 4 KiB

    float den = 0.f;
    #pragma unroll
    for (int c = 0; c < 64; ++c)                      // uniform -> scalar loads
        den += dpart[b * 64 + c];
    const float inv = 1.0f / den;

    f4 p = (f4)(0.f);
    #pragma unroll
    for (int k = 0; k < 16; ++k) {                    // wave w sums c = 4k+w
        int c = k * 4 + w;
        p += ppart4[(size_t)(b * 64 + c) * (DQ / 4) + lane];
    }
    pp[tid] = p;
    __syncthreads();
    f4 pv = (pp[lane] + pp[64 + lane]) + (pp[128 + lane] + pp[192 + lane]);
    pv *= inv;

    size_t base = (size_t)blk * 4096;                 // 4096 f4 of out/block
    #pragma unroll
    for (int k = 0; k < 16; ++k)
        __builtin_nontemporal_store(pv, &out4[base + k * 256 + tid]);
}

extern "C" void kernel_launch(void* const* d_in, const int* in_sizes, int n_in,
                              void* d_out, int out_size, void* d_ws, size_t ws_size,
                              hipStream_t stream) {
    const f4* h4 = (const f4*)d_in[0];           // [B,T,D]
    const f4* s4 = (const f4*)d_in[1];           // [B,T,J]
    f4* out4 = (f4*)d_out;                       // [B,T,D]

    float* ws = (float*)d_ws;
    float* dpart = ws;                           // NBLK1 floats
    float* ppart = ws + NBLK1;                   // NBLK1*DQ floats (2 MiB)

    k_fused_pool<<<NBLK1, NTHR, 0, stream>>>(s4, h4, dpart, ppart);
    k_reduce_bcast<<<NBLK2, NTHR, 0, stream>>>(dpart, (const f4*)ppart, out4);
}